// Round 1
// baseline (92.455 us; speedup 1.0000x reference)
//
#include <hip/hip_runtime.h>

#define DEPTH 8
#define NINT 255          // internal nodes
#define NLEAF 256
#define BATCH 2048
#define NCLS 200
#define EPS 1e-7f
#define TB 16             // batch tile per block in the GEMM kernel

// ---------------------------------------------------------------------------
// Kernel 1: S[l][c] = softmax(leaf_logits[l])  (linear domain), one wave/leaf.
// ---------------------------------------------------------------------------
__global__ __launch_bounds__(64) void leaf_softmax_kernel(
    const float* __restrict__ logits, float* __restrict__ S) {
    const int l = blockIdx.x;
    const int t = threadIdx.x;
    const float* row = logits + l * NCLS;

    float v[4];
    float m = -1e30f;
#pragma unroll
    for (int k = 0; k < 4; ++k) {
        int c = t + 64 * k;
        v[k] = (c < NCLS) ? row[c] : -1e30f;
        m = fmaxf(m, v[k]);
    }
#pragma unroll
    for (int off = 32; off >= 1; off >>= 1)
        m = fmaxf(m, __shfl_xor(m, off, 64));

    float e[4];
    float s = 0.f;
#pragma unroll
    for (int k = 0; k < 4; ++k) {
        e[k] = expf(v[k] - m);      // padded lanes: expf(huge negative) -> 0
        s += e[k];
    }
#pragma unroll
    for (int off = 32; off >= 1; off >>= 1)
        s += __shfl_xor(s, off, 64);

    const float inv = 1.0f / s;
#pragma unroll
    for (int k = 0; k < 4; ++k) {
        int c = t + 64 * k;
        if (c < NCLS) S[l * NCLS + c] = e[k] * inv;
    }
}

// ---------------------------------------------------------------------------
// Kernel 2: per block: 16 batch rows.
//   phase a: load sims slice -> LDS, compute p_left = log(1-exp(-a)) -> LDS
//   phase b: leaf path weights W[l][b] = exp(sum of 8 ancestor log-probs)
//   phase c: out[b,c] = log( sum_l W[l][b] * S[l][c] )  (4x4 register tile)
// ---------------------------------------------------------------------------
__global__ __launch_bounds__(256) void tree_gemm_kernel(
    const float* __restrict__ sims, const float* __restrict__ S,
    float* __restrict__ out) {
    __shared__ float pr_s[NINT * TB];   // p_right (raw sims, log-prob <= 0)
    __shared__ float pl_s[NINT * TB];   // p_left  = log(1 - exp(p_right)) stable
    __shared__ float W[NLEAF * TB];     // linear leaf weights, layout [l][b]

    const int tid = threadIdx.x;
    const int b0 = blockIdx.x * TB;

    // phase a ---------------------------------------------------------------
    for (int idx = tid; idx < NINT * TB; idx += 256) {
        const int node = idx >> 4;
        const int b = idx & (TB - 1);
        const float pr = sims[node * BATCH + b0 + b];
        const float a = EPS - pr;       // |p_right| + eps, pr <= 0
        const float pl = (a < 0.6931472f) ? logf(-expm1f(-a))
                                          : log1pf(-expf(-a));
        pr_s[idx] = pr;
        pl_s[idx] = pl;
    }
    __syncthreads();

    // phase b ---------------------------------------------------------------
    for (int idx = tid; idx < NLEAF * TB; idx += 256) {
        const int l = idx >> 4;
        const int b = idx & (TB - 1);
        float w = 0.f;
        int n = NINT + l;               // virtual heap id of leaf l
#pragma unroll
        for (int d = 0; d < DEPTH; ++d) {
            const int p = (n - 1) >> 1;
            const bool right = ((n & 1) == 0);   // n == 2p+2 -> right child
            w += right ? pr_s[p * TB + b] : pl_s[p * TB + b];
            n = p;
        }
        W[idx] = expf(w);
    }
    __syncthreads();

    // phase c ---------------------------------------------------------------
    const int tc = tid & 63;            // class group
    const int tb = tid >> 6;            // batch group
    const int c0 = tc * 4;              // 0..252 (>=200 idles)
    const int bb = tb * 4;              // 0,4,8,12
    if (c0 < NCLS) {
        float acc[4][4] = {};
#pragma unroll 4
        for (int l = 0; l < NLEAF; ++l) {
            const float4 s4 = *reinterpret_cast<const float4*>(S + l * NCLS + c0);
            const float4 w4 = *reinterpret_cast<const float4*>(&W[l * TB + bb]);
            const float sv[4] = {s4.x, s4.y, s4.z, s4.w};
            const float wv[4] = {w4.x, w4.y, w4.z, w4.w};
#pragma unroll
            for (int i = 0; i < 4; ++i)
#pragma unroll
                for (int j = 0; j < 4; ++j)
                    acc[i][j] += wv[i] * sv[j];
        }
#pragma unroll
        for (int i = 0; i < 4; ++i) {
            float4 o;
            o.x = logf(acc[i][0]);
            o.y = logf(acc[i][1]);
            o.z = logf(acc[i][2]);
            o.w = logf(acc[i][3]);
            *reinterpret_cast<float4*>(out + (b0 + bb + i) * NCLS + c0) = o;
        }
    }
}

extern "C" void kernel_launch(void* const* d_in, const int* in_sizes, int n_in,
                              void* d_out, int out_size, void* d_ws, size_t ws_size,
                              hipStream_t stream) {
    const float* sims = (const float*)d_in[0];     // [255, 2048] fp32
    const float* logits = (const float*)d_in[1];   // [256, 200]  fp32
    float* S = (float*)d_ws;                       // 256*200*4 = 204800 B scratch
    float* out = (float*)d_out;                    // [2048, 200] fp32

    leaf_softmax_kernel<<<NLEAF, 64, 0, stream>>>(logits, S);
    tree_gemm_kernel<<<BATCH / TB, 256, 0, stream>>>(sims, S, out);
}

// Round 2
// 80.901 us; speedup vs baseline: 1.1428x; 1.1428x over previous
//
#include <hip/hip_runtime.h>

#define DEPTH 8
#define NINT 255          // internal nodes
#define NLEAF 256
#define HALF 128          // leaves per gemm block (gridDim.y = 2)
#define BATCH 2048
#define NCLS 200
#define EPS 1e-7f
#define TB 16             // batch tile per block in the GEMM kernel

// ---------------------------------------------------------------------------
// Kernel 1: S[l][c] = softmax(leaf_logits[l])  (linear domain), one wave/leaf.
// ---------------------------------------------------------------------------
__global__ __launch_bounds__(64) void leaf_softmax_kernel(
    const float* __restrict__ logits, float* __restrict__ S) {
    const int l = blockIdx.x;
    const int t = threadIdx.x;
    const float* row = logits + l * NCLS;

    float v[4];
    float m = -1e30f;
#pragma unroll
    for (int k = 0; k < 4; ++k) {
        int c = t + 64 * k;
        v[k] = (c < NCLS) ? row[c] : -1e30f;
        m = fmaxf(m, v[k]);
    }
#pragma unroll
    for (int off = 32; off >= 1; off >>= 1)
        m = fmaxf(m, __shfl_xor(m, off, 64));

    float e[4];
    float s = 0.f;
#pragma unroll
    for (int k = 0; k < 4; ++k) {
        e[k] = expf(v[k] - m);      // padded lanes: expf(huge negative) -> 0
        s += e[k];
    }
#pragma unroll
    for (int off = 32; off >= 1; off >>= 1)
        s += __shfl_xor(s, off, 64);

    const float inv = 1.0f / s;
#pragma unroll
    for (int k = 0; k < 4; ++k) {
        int c = t + 64 * k;
        if (c < NCLS) S[l * NCLS + c] = e[k] * inv;
    }
}

// ---------------------------------------------------------------------------
// Kernel 2: grid (BATCH/TB, 2). Block (bx, h): 16 batch rows, leaf half h.
//   phase a: sims slice -> LDS, p_left = log(1-exp(-a)) -> LDS  (all 255 nodes)
//   phase b: leaf weights W[ll][b] = exp(path sum) for leaves [128h, 128h+128)
//   phase c: part[h][b][c] = sum_ll W[ll][b]*S[128h+ll][c]  (4x4 reg tile)
// ---------------------------------------------------------------------------
__global__ __launch_bounds__(256) void tree_gemm_partial(
    const float* __restrict__ sims, const float* __restrict__ S,
    float* __restrict__ part) {
    __shared__ float pr_s[NINT * TB];   // p_right (raw sims, log-prob <= 0)
    __shared__ float pl_s[NINT * TB];   // p_left  = log(1 - exp(p_right)) stable
    __shared__ float W[HALF * TB];      // linear leaf weights, layout [ll][b]

    const int tid = threadIdx.x;
    const int b0 = blockIdx.x * TB;
    const int h = blockIdx.y;

    // phase a ---------------------------------------------------------------
    for (int idx = tid; idx < NINT * TB; idx += 256) {
        const int node = idx >> 4;
        const int b = idx & (TB - 1);
        const float pr = sims[node * BATCH + b0 + b];
        const float a = EPS - pr;       // |p_right| + eps, pr <= 0
        const float pl = (a < 0.6931472f) ? logf(-expm1f(-a))
                                          : log1pf(-expf(-a));
        pr_s[idx] = pr;
        pl_s[idx] = pl;
    }
    __syncthreads();

    // phase b ---------------------------------------------------------------
    for (int idx = tid; idx < HALF * TB; idx += 256) {
        const int ll = idx >> 4;
        const int b = idx & (TB - 1);
        float w = 0.f;
        int n = NINT + h * HALF + ll;   // heap id of global leaf
#pragma unroll
        for (int d = 0; d < DEPTH; ++d) {
            const int p = (n - 1) >> 1;
            const bool right = ((n & 1) == 0);   // n == 2p+2 -> right child
            w += right ? pr_s[p * TB + b] : pl_s[p * TB + b];
            n = p;
        }
        W[idx] = expf(w);
    }
    __syncthreads();

    // phase c ---------------------------------------------------------------
    const int tc = tid & 63;            // class group
    const int tb = tid >> 6;            // batch group
    const int c0 = tc * 4;              // 0..252 (>=200 idles)
    const int bb = tb * 4;              // 0,4,8,12
    if (c0 < NCLS) {
        float acc[4][4] = {};
        const float* Sbase = S + (h * HALF) * NCLS + c0;
#pragma unroll 8
        for (int l = 0; l < HALF; ++l) {
            const float4 s4 = *reinterpret_cast<const float4*>(Sbase + l * NCLS);
            const float4 w4 = *reinterpret_cast<const float4*>(&W[l * TB + bb]);
            const float sv[4] = {s4.x, s4.y, s4.z, s4.w};
            const float wv[4] = {w4.x, w4.y, w4.z, w4.w};
#pragma unroll
            for (int i = 0; i < 4; ++i)
#pragma unroll
                for (int j = 0; j < 4; ++j)
                    acc[i][j] += wv[i] * sv[j];
        }
#pragma unroll
        for (int i = 0; i < 4; ++i) {
            float4 o;
            o.x = acc[i][0];
            o.y = acc[i][1];
            o.z = acc[i][2];
            o.w = acc[i][3];
            *reinterpret_cast<float4*>(part + ((size_t)h * BATCH + b0 + bb + i) * NCLS + c0) = o;
        }
    }
}

// ---------------------------------------------------------------------------
// Kernel 3: out = log(part0 + part1), float4 grid-exact (409600 / 1024 = 400)
// ---------------------------------------------------------------------------
__global__ __launch_bounds__(256) void finalize_kernel(
    const float* __restrict__ part, float* __restrict__ out) {
    const int i = (blockIdx.x * 256 + threadIdx.x) * 4;
    const float4 a = *reinterpret_cast<const float4*>(part + i);
    const float4 b = *reinterpret_cast<const float4*>(part + (size_t)BATCH * NCLS + i);
    float4 o;
    o.x = logf(a.x + b.x);
    o.y = logf(a.y + b.y);
    o.z = logf(a.z + b.z);
    o.w = logf(a.w + b.w);
    *reinterpret_cast<float4*>(out + i) = o;
}

extern "C" void kernel_launch(void* const* d_in, const int* in_sizes, int n_in,
                              void* d_out, int out_size, void* d_ws, size_t ws_size,
                              hipStream_t stream) {
    const float* sims = (const float*)d_in[0];     // [255, 2048] fp32
    const float* logits = (const float*)d_in[1];   // [256, 200]  fp32
    float* S = (float*)d_ws;                       // 256*200 floats = 204800 B
    float* part = S + NLEAF * NCLS;                // 2*2048*200 floats = 3.28 MB
    float* out = (float*)d_out;                    // [2048, 200] fp32

    leaf_softmax_kernel<<<NLEAF, 64, 0, stream>>>(logits, S);
    dim3 g2(BATCH / TB, 2);
    tree_gemm_partial<<<g2, 256, 0, stream>>>(sims, S, part);
    finalize_kernel<<<(BATCH * NCLS) / 1024, 256, 0, stream>>>(part, out);
}

// Round 3
// 76.403 us; speedup vs baseline: 1.2101x; 1.0589x over previous
//
#include <hip/hip_runtime.h>

#define DEPTH 8
#define NINT 255          // internal nodes
#define NLEAF 256
#define BATCH 2048
#define NCLS 200
#define EPS 1e-7f
#define TB 8              // batch rows per gemm block -> 256 blocks = 1/CU

// ---------------------------------------------------------------------------
// Kernel 1: S[l][c] = softmax(leaf_logits[l])  (linear domain), one wave/leaf.
// ---------------------------------------------------------------------------
__global__ __launch_bounds__(64) void leaf_softmax_kernel(
    const float* __restrict__ logits, float* __restrict__ S) {
    const int l = blockIdx.x;
    const int t = threadIdx.x;
    const float* row = logits + l * NCLS;

    float v[4];
    float m = -1e30f;
#pragma unroll
    for (int k = 0; k < 4; ++k) {
        int c = t + 64 * k;
        v[k] = (c < NCLS) ? row[c] : -1e30f;
        m = fmaxf(m, v[k]);
    }
#pragma unroll
    for (int off = 32; off >= 1; off >>= 1)
        m = fmaxf(m, __shfl_xor(m, off, 64));

    float e[4];
    float s = 0.f;
#pragma unroll
    for (int k = 0; k < 4; ++k) {
        e[k] = expf(v[k] - m);      // padded lanes: expf(huge negative) -> 0
        s += e[k];
    }
#pragma unroll
    for (int off = 32; off >= 1; off >>= 1)
        s += __shfl_xor(s, off, 64);

    const float inv = 1.0f / s;
#pragma unroll
    for (int k = 0; k < 4; ++k) {
        int c = t + 64 * k;
        if (c < NCLS) S[l * NCLS + c] = e[k] * inv;
    }
}

// ---------------------------------------------------------------------------
// Kernel 2 (fused gemm + log epilogue): 256 blocks, 8 batch rows each.
//   phase a: sims slice -> LDS, p_left = log(1-exp(-a)) -> LDS  (255 nodes)
//   phase b: leaf weights W[l][b] = exp(path sum), all 256 leaves
//   phase c: out[b,c] = log( sum_l W[l][b]*S[l][c] )  (2x4 reg tile, unroll 16)
// ---------------------------------------------------------------------------
__global__ __launch_bounds__(256) void tree_gemm_fused(
    const float* __restrict__ sims, const float* __restrict__ S,
    float* __restrict__ out) {
    __shared__ float pr_s[NINT * TB];   // p_right (raw sims, log-prob <= 0)
    __shared__ float pl_s[NINT * TB];   // p_left  = log(1 - exp(p_right)) stable
    __shared__ float W[NLEAF * TB];     // linear leaf weights, layout [l][b]

    const int tid = threadIdx.x;
    const int b0 = blockIdx.x * TB;

    // phase a ---------------------------------------------------------------
    for (int idx = tid; idx < NINT * TB; idx += 256) {
        const int node = idx >> 3;
        const int b = idx & (TB - 1);
        const float pr = sims[node * BATCH + b0 + b];
        const float a = EPS - pr;       // |p_right| + eps, pr <= 0
        const float pl = (a < 0.6931472f) ? logf(-expm1f(-a))
                                          : log1pf(-expf(-a));
        pr_s[idx] = pr;
        pl_s[idx] = pl;
    }
    __syncthreads();

    // phase b ---------------------------------------------------------------
    for (int idx = tid; idx < NLEAF * TB; idx += 256) {
        const int l = idx >> 3;
        const int b = idx & (TB - 1);
        float w = 0.f;
        int n = NINT + l;               // heap id of leaf l
#pragma unroll
        for (int d = 0; d < DEPTH; ++d) {
            const int p = (n - 1) >> 1;
            const bool right = ((n & 1) == 0);   // n == 2p+2 -> right child
            w += right ? pr_s[p * TB + b] : pl_s[p * TB + b];
            n = p;
        }
        W[idx] = expf(w);
    }
    __syncthreads();

    // phase c ---------------------------------------------------------------
    const int tc = tid & 63;            // class group
    const int tb = tid >> 6;            // batch group (0..3)
    const int c0 = tc * 4;              // 0..252 (>=200 idles)
    const int bb = tb * 2;              // rows {0,1},{2,3},{4,5},{6,7}
    if (c0 < NCLS) {
        float acc[2][4] = {};
#pragma unroll 16
        for (int l = 0; l < NLEAF; ++l) {
            const float4 s4 = *reinterpret_cast<const float4*>(S + l * NCLS + c0);
            const float2 w2 = *reinterpret_cast<const float2*>(&W[l * TB + bb]);
            const float sv[4] = {s4.x, s4.y, s4.z, s4.w};
            const float wv[2] = {w2.x, w2.y};
#pragma unroll
            for (int i = 0; i < 2; ++i)
#pragma unroll
                for (int j = 0; j < 4; ++j)
                    acc[i][j] += wv[i] * sv[j];
        }
#pragma unroll
        for (int i = 0; i < 2; ++i) {
            float4 o;
            o.x = logf(acc[i][0]);
            o.y = logf(acc[i][1]);
            o.z = logf(acc[i][2]);
            o.w = logf(acc[i][3]);
            *reinterpret_cast<float4*>(out + (size_t)(b0 + bb + i) * NCLS + c0) = o;
        }
    }
}

extern "C" void kernel_launch(void* const* d_in, const int* in_sizes, int n_in,
                              void* d_out, int out_size, void* d_ws, size_t ws_size,
                              hipStream_t stream) {
    const float* sims = (const float*)d_in[0];     // [255, 2048] fp32
    const float* logits = (const float*)d_in[1];   // [256, 200]  fp32
    float* S = (float*)d_ws;                       // 256*200 floats = 204800 B
    float* out = (float*)d_out;                    // [2048, 200] fp32

    leaf_softmax_kernel<<<NLEAF, 64, 0, stream>>>(logits, S);
    tree_gemm_fused<<<BATCH / TB, 256, 0, stream>>>(sims, S, out);
}

// Round 4
// 73.580 us; speedup vs baseline: 1.2565x; 1.0384x over previous
//
#include <hip/hip_runtime.h>

#define DEPTH 8
#define NINT 255          // internal nodes
#define NLEAF 256
#define BATCH 2048
#define NCLS 200
#define EPS 1e-7f
#define TB 8              // batch rows per block -> 256 blocks = 1/CU
#define LPAD 264          // padded leaf-dim row length in bf16 elems (528 B, 16B-aligned, 132 dwords -> uniform banks)
#define NTILE 13          // ceil(200/16) class tiles

typedef float f32x4 __attribute__((ext_vector_type(4)));
typedef __bf16 bf16x8 __attribute__((ext_vector_type(8)));

static __device__ __forceinline__ unsigned short f2bf(float f) {
    unsigned int u = __builtin_bit_cast(unsigned int, f);
    u += 0x7fffu + ((u >> 16) & 1u);          // RNE; inputs are finite positives
    return (unsigned short)(u >> 16);
}

// out[b,c] = log( sum_l exp(path(l,b)) / Z_l * exp(logit[l,c]) )
//   A (MFMA) = W^T[b][l] = exp(path)/Z_l   (16 x 256, rows 8..15 zero)
//   B (MFMA) = E^T[c][l]^T i.e. E[l][c] = exp(logit), stored transposed [c][l]
__global__ __launch_bounds__(256) void tree_fused(
    const float* __restrict__ sims, const float* __restrict__ logits,
    float* __restrict__ out) {
    __shared__ unsigned short Et[(NTILE * 16) * LPAD]; // 208 rows: E^T[c][l], bf16
    __shared__ unsigned short Wt[16 * LPAD];           // W^T[b][l], bf16
    __shared__ float pr_s[NINT * TB];
    __shared__ float pl_s[NINT * TB];
    __shared__ float invZ[NLEAF];

    const int tid = threadIdx.x;
    const int b0 = blockIdx.x * TB;

    // --- issue sims loads early (HBM-cold) so phase-0 compute hides them ---
    float prv[8];
#pragma unroll
    for (int p = 0; p < 8; ++p) {
        const int idx = tid + 256 * p;
        if (idx < NINT * TB)
            prv[p] = sims[(idx >> 3) * BATCH + b0 + (idx & 7)];
    }

    // --- zero the pad rows MFMA will read (W rows 8..15, E rows 200..207) ---
    {
        unsigned int* wz = (unsigned int*)(Wt + 8 * LPAD);
        unsigned int* ez = (unsigned int*)(Et + 200 * LPAD);
        for (int i = tid; i < (8 * LPAD) / 2; i += 256) { wz[i] = 0u; ez[i] = 0u; }
    }

    // --- phase 0: thread t = leaf t: E^T[c][t] = exp(logit[t][c]); Z_t ---
    {
        const float4* lr = (const float4*)(logits + tid * NCLS);
        float Z = 0.f;
        for (int j = 0; j < NCLS / 4; ++j) {
            const float4 v = lr[j];
            const float e0 = __expf(v.x), e1 = __expf(v.y),
                        e2 = __expf(v.z), e3 = __expf(v.w);
            Z += (e0 + e1) + (e2 + e3);
            const int c = 4 * j;
            Et[(c + 0) * LPAD + tid] = f2bf(e0);
            Et[(c + 1) * LPAD + tid] = f2bf(e1);
            Et[(c + 2) * LPAD + tid] = f2bf(e2);
            Et[(c + 3) * LPAD + tid] = f2bf(e3);
        }
        invZ[tid] = 1.0f / Z;
    }

    // --- phase a: pr / stable p_left -> LDS ---
#pragma unroll
    for (int p = 0; p < 8; ++p) {
        const int idx = tid + 256 * p;
        if (idx < NINT * TB) {
            const float pr = prv[p];
            const float a = EPS - pr;       // |p_right| + eps, pr <= 0
            const float pl = (a < 0.6931472f) ? logf(-expm1f(-a))
                                              : log1pf(-expf(-a));
            pr_s[idx] = pr;
            pl_s[idx] = pl;
        }
    }
    __syncthreads();

    // --- phase b: W^T[b][l] = exp(path)/Z_l (bf16), rows 0..7 ---
#pragma unroll
    for (int p = 0; p < 8; ++p) {
        const int idx = tid + 256 * p;      // l = idx>>3, b = idx&7
        const int l = idx >> 3;
        const int b = idx & 7;
        float w = 0.f;
        int n = NINT + l;                   // heap id of leaf l
#pragma unroll
        for (int d = 0; d < DEPTH; ++d) {
            const int par = (n - 1) >> 1;
            w += ((n & 1) == 0) ? pr_s[par * TB + b] : pl_s[par * TB + b];
            n = par;
        }
        Wt[b * LPAD + l] = f2bf(__expf(w) * invZ[l]);
    }
    __syncthreads();

    // --- phase c: MFMA 16x16x32 bf16, K=256 (8 steps), 13 class tiles / 4 waves
    const int lane = tid & 63;
    const int wave = tid >> 6;
    const int mn = lane & 15;               // A row (batch m) == B/D col (class n)
    const int quad = lane >> 4;

    f32x4 acc0 = {0.f, 0.f, 0.f, 0.f};
    f32x4 acc1 = {0.f, 0.f, 0.f, 0.f};
    f32x4 acc2 = {0.f, 0.f, 0.f, 0.f};
    f32x4 acc3 = {0.f, 0.f, 0.f, 0.f};
    const int t0 = wave, t1 = wave + 4, t2 = wave + 8, t3 = wave + 12;

#pragma unroll
    for (int s = 0; s < 8; ++s) {
        const int ko = s * 32 + quad * 8;   // k offset (elems); A/B k = quad*8+j
        const bf16x8 a = *(const bf16x8*)(Wt + mn * LPAD + ko);
        const bf16x8 bv0 = *(const bf16x8*)(Et + (t0 * 16 + mn) * LPAD + ko);
        acc0 = __builtin_amdgcn_mfma_f32_16x16x32_bf16(a, bv0, acc0, 0, 0, 0);
        const bf16x8 bv1 = *(const bf16x8*)(Et + (t1 * 16 + mn) * LPAD + ko);
        acc1 = __builtin_amdgcn_mfma_f32_16x16x32_bf16(a, bv1, acc1, 0, 0, 0);
        const bf16x8 bv2 = *(const bf16x8*)(Et + (t2 * 16 + mn) * LPAD + ko);
        acc2 = __builtin_amdgcn_mfma_f32_16x16x32_bf16(a, bv2, acc2, 0, 0, 0);
        if (wave == 0) {                    // tile 12 (classes 192..207)
            const bf16x8 bv3 = *(const bf16x8*)(Et + (t3 * 16 + mn) * LPAD + ko);
            acc3 = __builtin_amdgcn_mfma_f32_16x16x32_bf16(a, bv3, acc3, 0, 0, 0);
        }
    }

    // --- epilogue: D col = lane&15, row = quad*4 + reg; valid rows 0..7 ---
    if (quad < 2) {
        const int rbase = b0 + quad * 4;
#pragma unroll
        for (int i = 0; i < 4; ++i) {
            const int t = (i == 0) ? t0 : (i == 1) ? t1 : (i == 2) ? t2 : t3;
            if (t >= NTILE) continue;
            const f32x4 acc = (i == 0) ? acc0 : (i == 1) ? acc1
                            : (i == 2) ? acc2 : acc3;
            const int c = t * 16 + mn;
            if (c < NCLS) {
#pragma unroll
                for (int r = 0; r < 4; ++r)
                    out[(size_t)(rbase + r) * NCLS + c] = __logf(acc[r]);
            }
        }
    }
}

extern "C" void kernel_launch(void* const* d_in, const int* in_sizes, int n_in,
                              void* d_out, int out_size, void* d_ws, size_t ws_size,
                              hipStream_t stream) {
    const float* sims = (const float*)d_in[0];     // [255, 2048] fp32
    const float* logits = (const float*)d_in[1];   // [256, 200]  fp32
    float* out = (float*)d_out;                    // [2048, 200] fp32
    tree_fused<<<BATCH / TB, 256, 0, stream>>>(sims, logits, out);
}

// Round 5
// 70.474 us; speedup vs baseline: 1.3119x; 1.0441x over previous
//
#include <hip/hip_runtime.h>

#define DEPTH 8
#define NINT 255          // internal nodes
#define NLEAF 256
#define BATCH 2048
#define NCLS 200
#define EPS 1e-7f
#define TB 8              // batch rows per block -> 256 blocks = 1/CU
#define LPAD 264          // padded leaf-dim row length in bf16 elems (528 B, 16B-aligned)
#define NTILE 13          // ceil(200/16) class tiles

typedef float f32x4 __attribute__((ext_vector_type(4)));
typedef __bf16 bf16x8 __attribute__((ext_vector_type(8)));

// fast bf16 pack: round-half-up (add 0x8000, shift). Max rel err 2^-9 = 0.2%,
// -> <=0.004 abs error after the final log; threshold is 0.13. 2 VALU insts
// vs 4 for full RNE (208 packs/thread -> ~1600 cycles saved per wave).
static __device__ __forceinline__ unsigned short f2bf(float f) {
    unsigned int u = __builtin_bit_cast(unsigned int, f);
    return (unsigned short)((u + 0x8000u) >> 16);
}

// out[b,c] = log( sum_l exp(path(l,b)) / Z_l * exp(logit[l,c]) )
//   A (MFMA) = W^T[b][l] = exp(path)/Z_l   (16 x 256, rows 8..15 zero)
//   B (MFMA) = E^T[c][l]  (E[l][c] = exp(logit), stored transposed)
__global__ __launch_bounds__(256) void tree_fused(
    const float* __restrict__ sims, const float* __restrict__ logits,
    float* __restrict__ out) {
    __shared__ unsigned short Et[(NTILE * 16) * LPAD]; // 208 rows: E^T[c][l], bf16
    __shared__ unsigned short Wt[16 * LPAD];           // W^T[b][l], bf16
    __shared__ float pr_s[NINT * TB];
    __shared__ float pl_s[NINT * TB];
    __shared__ float invZ[NLEAF];

    const int tid = threadIdx.x;
    const int b0 = blockIdx.x * TB;

    // --- issue sims loads early (HBM-cold) so phase-0 compute hides them ---
    float prv[8];
#pragma unroll
    for (int p = 0; p < 8; ++p) {
        const int idx = tid + 256 * p;
        if (idx < NINT * TB)
            prv[p] = sims[(idx >> 3) * BATCH + b0 + (idx & 7)];
    }

    // --- zero the pad rows MFMA will read (W rows 8..15, E rows 200..207) ---
    {
        unsigned int* wz = (unsigned int*)(Wt + 8 * LPAD);
        unsigned int* ez = (unsigned int*)(Et + 200 * LPAD);
        for (int i = tid; i < (8 * LPAD) / 2; i += 256) { wz[i] = 0u; ez[i] = 0u; }
    }

    // --- phase 0: thread t = leaf t: E^T[c][t] = exp(logit[t][c]); Z_t ---
    {
        const float4* lr = (const float4*)(logits + tid * NCLS);
        float Z = 0.f;
        for (int j = 0; j < NCLS / 4; ++j) {
            const float4 v = lr[j];
            const float e0 = __expf(v.x), e1 = __expf(v.y),
                        e2 = __expf(v.z), e3 = __expf(v.w);
            Z += (e0 + e1) + (e2 + e3);
            const int c = 4 * j;
            Et[(c + 0) * LPAD + tid] = f2bf(e0);
            Et[(c + 1) * LPAD + tid] = f2bf(e1);
            Et[(c + 2) * LPAD + tid] = f2bf(e2);
            Et[(c + 3) * LPAD + tid] = f2bf(e3);
        }
        invZ[tid] = __builtin_amdgcn_rcpf(Z);   // Z in [200e-3, 200e3]: safe range
    }

    // --- phase a: pr / p_left -> LDS, all-hardware transcendentals.
    // pl = log(1 - exp(pr-EPS)): worst pr=-0.01 -> arg ~0.00995, expf rel err
    // ~1ulp -> log abs err ~6e-6. No expm1/log1p libcalls (saves ~800 cyc). ---
#pragma unroll
    for (int p = 0; p < 8; ++p) {
        const int idx = tid + 256 * p;
        if (idx < NINT * TB) {
            const float pr = prv[p];
            const float pl = __logf(1.0f - __expf(pr - EPS));
            pr_s[idx] = pr;
            pl_s[idx] = pl;
        }
    }
    __syncthreads();

    // --- phase b: W^T[b][l] = exp(path)/Z_l (bf16), rows 0..7 ---
#pragma unroll
    for (int p = 0; p < 8; ++p) {
        const int idx = tid + 256 * p;      // l = idx>>3, b = idx&7
        const int l = idx >> 3;
        const int b = idx & 7;
        float w = 0.f;
        int n = NINT + l;                   // heap id of leaf l
#pragma unroll
        for (int d = 0; d < DEPTH; ++d) {
            const int par = (n - 1) >> 1;
            w += ((n & 1) == 0) ? pr_s[par * TB + b] : pl_s[par * TB + b];
            n = par;
        }
        Wt[b * LPAD + l] = f2bf(__expf(w) * invZ[l]);
    }
    __syncthreads();

    // --- phase c: MFMA 16x16x32 bf16, K=256 (8 steps), 13 class tiles / 4 waves
    const int lane = tid & 63;
    const int wave = tid >> 6;
    const int mn = lane & 15;               // A row (batch m) == B/D col (class n)
    const int quad = lane >> 4;

    f32x4 acc0 = {0.f, 0.f, 0.f, 0.f};
    f32x4 acc1 = {0.f, 0.f, 0.f, 0.f};
    f32x4 acc2 = {0.f, 0.f, 0.f, 0.f};
    f32x4 acc3 = {0.f, 0.f, 0.f, 0.f};
    const int t0 = wave, t1 = wave + 4, t2 = wave + 8, t3 = wave + 12;

#pragma unroll
    for (int s = 0; s < 8; ++s) {
        const int ko = s * 32 + quad * 8;   // k offset (elems); A/B k = quad*8+j
        const bf16x8 a = *(const bf16x8*)(Wt + mn * LPAD + ko);
        const bf16x8 bv0 = *(const bf16x8*)(Et + (t0 * 16 + mn) * LPAD + ko);
        acc0 = __builtin_amdgcn_mfma_f32_16x16x32_bf16(a, bv0, acc0, 0, 0, 0);
        const bf16x8 bv1 = *(const bf16x8*)(Et + (t1 * 16 + mn) * LPAD + ko);
        acc1 = __builtin_amdgcn_mfma_f32_16x16x32_bf16(a, bv1, acc1, 0, 0, 0);
        const bf16x8 bv2 = *(const bf16x8*)(Et + (t2 * 16 + mn) * LPAD + ko);
        acc2 = __builtin_amdgcn_mfma_f32_16x16x32_bf16(a, bv2, acc2, 0, 0, 0);
        if (wave == 0) {                    // tile 12 (classes 192..207)
            const bf16x8 bv3 = *(const bf16x8*)(Et + (t3 * 16 + mn) * LPAD + ko);
            acc3 = __builtin_amdgcn_mfma_f32_16x16x32_bf16(a, bv3, acc3, 0, 0, 0);
        }
    }

    // --- epilogue: D col = lane&15, row = quad*4 + reg; valid rows 0..7 ---
    if (quad < 2) {
        const int rbase = b0 + quad * 4;
#pragma unroll
        for (int i = 0; i < 4; ++i) {
            const int t = (i == 0) ? t0 : (i == 1) ? t1 : (i == 2) ? t2 : t3;
            if (t >= NTILE) continue;
            const f32x4 acc = (i == 0) ? acc0 : (i == 1) ? acc1
                            : (i == 2) ? acc2 : acc3;
            const int c = t * 16 + mn;
            if (c < NCLS) {
#pragma unroll
                for (int r = 0; r < 4; ++r)
                    out[(size_t)(rbase + r) * NCLS + c] = __logf(acc[r]);
            }
        }
    }
}

extern "C" void kernel_launch(void* const* d_in, const int* in_sizes, int n_in,
                              void* d_out, int out_size, void* d_ws, size_t ws_size,
                              hipStream_t stream) {
    const float* sims = (const float*)d_in[0];     // [255, 2048] fp32
    const float* logits = (const float*)d_in[1];   // [256, 200]  fp32
    float* out = (float*)d_out;                    // [2048, 200] fp32
    tree_fused<<<BATCH / TB, 256, 0, stream>>>(sims, logits, out);
}